// Round 1
// baseline (1374.026 us; speedup 1.0000x reference)
//
#include <hip/hip_runtime.h>

// Problem constants (from reference setup_inputs)
#define NN 200000
#define EE 6400000L

// ---------------------------------------------------------------------------
// Edge-index dtype hedge: reference uses int64, harness doc says int32.
// Detect on device: if the buffer is int64 (values < 2^31), every odd 32-bit
// word (high half) is zero. For int32 random indices in [0,200000), odd words
// are actual values and are ~never all zero across 8192 samples.
// flag = 1 -> int64 (word index = elem << 1), flag = 0 -> int32.
// ---------------------------------------------------------------------------
__global__ void k_detect(const int* __restrict__ w, int* __restrict__ flag) {
    __shared__ int any;
    if (threadIdx.x == 0) any = 0;
    __syncthreads();
    int found = 0;
    for (int i = threadIdx.x; i < 8192; i += 256) {
        if (w[2 * i + 1] != 0) found = 1;
    }
    if (found) atomicOr(&any, 1);
    __syncthreads();
    if (threadIdx.x == 0) flag[0] = any ? 0 : 1;
}

__global__ void k_init_dis(float* __restrict__ dis, int n) {
    int i = blockIdx.x * 256 + threadIdx.x;
    if (i < n) dis[i] = 1.0f;
}

// deg[dst] += 1 per edge (float atomics are exact for counts < 2^24)
__global__ void k_count(const int* __restrict__ ew, const int* __restrict__ flag,
                        float* __restrict__ dis, long e) {
    long i = (long)blockIdx.x * 256 + threadIdx.x;
    if (i >= e) return;
    int shift = *flag;
    int d = ew[(EE + i) << shift];
    atomicAdd(&dis[d], 1.0f);
}

__global__ void k_rsqrt(float* __restrict__ dis, int n) {
    int i = blockIdx.x * 256 + threadIdx.x;
    if (i < n) dis[i] = rsqrtf(dis[i]);
}

// Layer 1: hw = x @ W1  (x: [N,256], W1: [256,16])
// Also writes agg init: agg[i] = hw[i]*dis[i]^2 + b  (self-loop + bias)
__global__ __launch_bounds__(256) void k_mm1(
    const float* __restrict__ x, const float* __restrict__ W,
    const float* __restrict__ b, const float* __restrict__ dis,
    float* __restrict__ hw, float* __restrict__ agg, int n) {
    __shared__ float Wl[256 * 16];
    int t = threadIdx.x;
#pragma unroll
    for (int i = 0; i < 4; ++i)
        ((float4*)Wl)[t + i * 256] = ((const float4*)W)[t + i * 256];
    __syncthreads();

    int node = blockIdx.x * 256 + t;
    if (node >= n) return;

    const float4* xr = (const float4*)(x + (long)node * 256);
    float acc[16];
#pragma unroll
    for (int o = 0; o < 16; ++o) acc[o] = 0.f;

#pragma unroll 8
    for (int kk = 0; kk < 64; ++kk) {
        float4 xv = xr[kk];
#pragma unroll
        for (int q = 0; q < 4; ++q) {
            float xs = (q == 0) ? xv.x : (q == 1) ? xv.y : (q == 2) ? xv.z : xv.w;
            const float4* wr = (const float4*)&Wl[(kk * 4 + q) * 16];
#pragma unroll
            for (int oo = 0; oo < 4; ++oo) {
                float4 wv = wr[oo];
                acc[oo * 4 + 0] = fmaf(xs, wv.x, acc[oo * 4 + 0]);
                acc[oo * 4 + 1] = fmaf(xs, wv.y, acc[oo * 4 + 1]);
                acc[oo * 4 + 2] = fmaf(xs, wv.z, acc[oo * 4 + 2]);
                acc[oo * 4 + 3] = fmaf(xs, wv.w, acc[oo * 4 + 3]);
            }
        }
    }

    float dv = dis[node];
    float d2 = dv * dv;
    float4* hwo = (float4*)(hw + (long)node * 16);
    float4* ago = (float4*)(agg + (long)node * 16);
    const float4* bb = (const float4*)b;
#pragma unroll
    for (int oo = 0; oo < 4; ++oo) {
        float4 v = make_float4(acc[oo * 4 + 0], acc[oo * 4 + 1], acc[oo * 4 + 2], acc[oo * 4 + 3]);
        hwo[oo] = v;
        float4 bv = bb[oo];
        ago[oo] = make_float4(fmaf(v.x, d2, bv.x), fmaf(v.y, d2, bv.y),
                              fmaf(v.z, d2, bv.z), fmaf(v.w, d2, bv.w));
    }
}

// Layers 2: hw = relu(h) @ W (16x16), same fused epilogue.
// NOTE: h and agg alias (same buffer) -> no __restrict__ on them.
__global__ __launch_bounds__(256) void k_mm2(
    const float* h, const float* __restrict__ W,
    const float* __restrict__ b, const float* __restrict__ dis,
    float* __restrict__ hw, float* agg, int n) {
    __shared__ float Wl[256];
    if (threadIdx.x < 64) ((float4*)Wl)[threadIdx.x] = ((const float4*)W)[threadIdx.x];
    __syncthreads();

    int node = blockIdx.x * 256 + threadIdx.x;
    if (node >= n) return;

    float hv[16];
    const float4* hr = (const float4*)(h + (long)node * 16);
#pragma unroll
    for (int i = 0; i < 4; ++i) {
        float4 v = hr[i];
        hv[i * 4 + 0] = fmaxf(v.x, 0.f);
        hv[i * 4 + 1] = fmaxf(v.y, 0.f);
        hv[i * 4 + 2] = fmaxf(v.z, 0.f);
        hv[i * 4 + 3] = fmaxf(v.w, 0.f);
    }

    float acc[16];
#pragma unroll
    for (int o = 0; o < 16; ++o) acc[o] = 0.f;
#pragma unroll
    for (int k = 0; k < 16; ++k) {
        float xs = hv[k];
#pragma unroll
        for (int o = 0; o < 16; ++o) acc[o] = fmaf(xs, Wl[k * 16 + o], acc[o]);
    }

    float dv = dis[node];
    float d2 = dv * dv;
    float4* hwo = (float4*)(hw + (long)node * 16);
    float4* ago = (float4*)(agg + (long)node * 16);
    const float4* bb = (const float4*)b;
#pragma unroll
    for (int oo = 0; oo < 4; ++oo) {
        float4 v = make_float4(acc[oo * 4 + 0], acc[oo * 4 + 1], acc[oo * 4 + 2], acc[oo * 4 + 3]);
        hwo[oo] = v;
        float4 bv = bb[oo];
        ago[oo] = make_float4(fmaf(v.x, d2, bv.x), fmaf(v.y, d2, bv.y),
                              fmaf(v.z, d2, bv.z), fmaf(v.w, d2, bv.w));
    }
}

// Layer 3: hw3 = relu(h) @ W3 (16x1); out init = hw3*dis^2 + b3
__global__ __launch_bounds__(256) void k_mm3(
    const float* __restrict__ h, const float* __restrict__ W,
    const float* __restrict__ b, const float* __restrict__ dis,
    float* __restrict__ hw3, float* __restrict__ out, int n) {
    int node = blockIdx.x * 256 + threadIdx.x;
    if (node >= n) return;
    const float4* hr = (const float4*)(h + (long)node * 16);
    float acc = 0.f;
#pragma unroll
    for (int i = 0; i < 4; ++i) {
        float4 v = hr[i];
        acc = fmaf(fmaxf(v.x, 0.f), W[i * 4 + 0], acc);
        acc = fmaf(fmaxf(v.y, 0.f), W[i * 4 + 1], acc);
        acc = fmaf(fmaxf(v.z, 0.f), W[i * 4 + 2], acc);
        acc = fmaf(fmaxf(v.w, 0.f), W[i * 4 + 3], acc);
    }
    hw3[node] = acc;
    float dv = dis[node];
    out[node] = fmaf(acc, dv * dv, b[0]);
}

// Edge scatter, 16 channels: thread = (edge, ch). 16 lanes of an edge hit 16
// consecutive dwords for both the gather (hw[src]) and the atomic (agg[dst]).
__global__ __launch_bounds__(256) void k_scat16(
    const int* __restrict__ ew, const int* __restrict__ flag,
    const float* __restrict__ dis, const float* __restrict__ hw,
    float* __restrict__ agg, long total) {
    long tid = (long)blockIdx.x * 256 + threadIdx.x;
    if (tid >= total) return;
    int shift = *flag;
    long e = tid >> 4;
    int ch = (int)(tid & 15);
    int s = ew[e << shift];
    int d = ew[(EE + e) << shift];
    float nrm = dis[s] * dis[d];
    atomicAdd(&agg[(long)d * 16 + ch], nrm * hw[(long)s * 16 + ch]);
}

// Edge scatter, 1 channel (layer 3)
__global__ __launch_bounds__(256) void k_scat1(
    const int* __restrict__ ew, const int* __restrict__ flag,
    const float* __restrict__ dis, const float* __restrict__ hw3,
    float* __restrict__ out, long e) {
    long i = (long)blockIdx.x * 256 + threadIdx.x;
    if (i >= e) return;
    int shift = *flag;
    int s = ew[i << shift];
    int d = ew[(EE + i) << shift];
    atomicAdd(&out[d], dis[s] * dis[d] * hw3[s]);
}

extern "C" void kernel_launch(void* const* d_in, const int* in_sizes, int n_in,
                              void* d_out, int out_size, void* d_ws, size_t ws_size,
                              hipStream_t stream) {
    const float* x  = (const float*)d_in[0];
    const int*   ew = (const int*)d_in[1];
    const float* W1 = (const float*)d_in[2];
    const float* b1 = (const float*)d_in[3];
    const float* W2 = (const float*)d_in[4];
    const float* b2 = (const float*)d_in[5];
    const float* W3 = (const float*)d_in[6];
    const float* b3 = (const float*)d_in[7];
    float* out = (float*)d_out;

    // Workspace layout (floats): dis[204800] | bufA[3276800] | bufB[3276800] | flag
    float* dis  = (float*)d_ws;
    float* bufA = dis + 204800;       // hw (and hw3 in layer 3)
    float* bufB = bufA + 3276800;     // agg / h
    int*   flag = (int*)(bufB + 3276800);

    const int n = NN;
    const long e = EE;
    int  nb = (n + 255) / 256;              // 782
    int  eb = (int)((e + 255) / 256);       // 25000
    int  sb = (int)((e * 16 + 255) / 256);  // 400000

    k_detect<<<1, 256, 0, stream>>>(ew, flag);
    k_init_dis<<<nb, 256, 0, stream>>>(dis, n);
    k_count<<<eb, 256, 0, stream>>>(ew, flag, dis, e);
    k_rsqrt<<<nb, 256, 0, stream>>>(dis, n);

    // Layer 1
    k_mm1<<<nb, 256, 0, stream>>>(x, W1, b1, dis, bufA, bufB, n);
    k_scat16<<<sb, 256, 0, stream>>>(ew, flag, dis, bufA, bufB, e * 16);

    // Layer 2 (relu fused into matmul input read)
    k_mm2<<<nb, 256, 0, stream>>>(bufB, W2, b2, dis, bufA, bufB, n);
    k_scat16<<<sb, 256, 0, stream>>>(ew, flag, dis, bufA, bufB, e * 16);

    // Layer 3
    k_mm3<<<nb, 256, 0, stream>>>(bufB, W3, b3, dis, bufA, out, n);
    k_scat1<<<eb, 256, 0, stream>>>(ew, flag, dis, bufA, out, e);
}

// Round 2
// 964.970 us; speedup vs baseline: 1.4239x; 1.4239x over previous
//
#include <hip/hip_runtime.h>

#define NN 200000
#define EE 6400000L

// ---------------------------------------------------------------------------
// Edge-index dtype hedge (int64 vs int32): if int64 with values < 2^31, every
// odd 32-bit word is zero. flag=1 -> int64 (word idx = elem<<1), 0 -> int32.
// ---------------------------------------------------------------------------
__global__ void k_detect(const int* __restrict__ w, int* __restrict__ flag) {
    __shared__ int any;
    if (threadIdx.x == 0) any = 0;
    __syncthreads();
    int found = 0;
    for (int i = threadIdx.x; i < 8192; i += 256)
        if (w[2 * i + 1] != 0) found = 1;
    if (found) atomicOr(&any, 1);
    __syncthreads();
    if (threadIdx.x == 0) flag[0] = any ? 0 : 1;
}

// deg[dst]++ per edge (int atomics, 800KB table -> L2-resident)
__global__ void k_count(const int* __restrict__ ew, const int* __restrict__ flag,
                        int* __restrict__ deg, long e) {
    long i = (long)blockIdx.x * 256 + threadIdx.x;
    if (i >= e) return;
    int shift = *flag;
    int d = ew[(EE + i) << shift];
    atomicAdd(&deg[d], 1);
}

__global__ void k_rsqrt(const int* __restrict__ deg, float* __restrict__ dis, int n) {
    int i = blockIdx.x * 256 + threadIdx.x;
    if (i < n) dis[i] = rsqrtf((float)(deg[i] + 1));
}

// ---- 3-kernel exclusive scan of deg[n] -> off[n]; also copies into cursor ----
__global__ void k_scan1(const int* __restrict__ deg, int* __restrict__ excl,
                        int* __restrict__ bsum, int n) {
    int t = threadIdx.x;
    int gid = blockIdx.x * 256 + t;
    int v = (gid < n) ? deg[gid] : 0;
    int lane = t & 63, wid = t >> 6;
    int s = v;
#pragma unroll
    for (int o = 1; o < 64; o <<= 1) {
        int u = __shfl_up(s, o, 64);
        if (lane >= o) s += u;
    }
    __shared__ int ws[4];
    if (lane == 63) ws[wid] = s;
    __syncthreads();
    int add = 0;
    for (int w = 0; w < wid; ++w) add += ws[w];
    if (gid < n) excl[gid] = s + add - v;
    if (t == 255) bsum[blockIdx.x] = s + add;
}

__global__ void k_scan2(int* __restrict__ bsum, int nb) {
    int t = threadIdx.x;  // 1024 threads, nb <= 1024
    int v = (t < nb) ? bsum[t] : 0;
    int lane = t & 63, wid = t >> 6;
    int s = v;
#pragma unroll
    for (int o = 1; o < 64; o <<= 1) {
        int u = __shfl_up(s, o, 64);
        if (lane >= o) s += u;
    }
    __shared__ int ws[16];
    if (lane == 63) ws[wid] = s;
    __syncthreads();
    int add = 0;
    for (int w = 0; w < wid; ++w) add += ws[w];
    if (t < nb) bsum[t] = s + add - v;  // exclusive block offsets
}

__global__ void k_scan3(int* __restrict__ excl, const int* __restrict__ bsum,
                        int* __restrict__ cursor, int n) {
    int gid = blockIdx.x * 256 + threadIdx.x;
    if (gid < n) {
        int v = excl[gid] + bsum[blockIdx.x];
        excl[gid] = v;
        cursor[gid] = v;
    }
}

// Fill CSR: csr[pos] = {src, dis[src]*dis[dst]} grouped by dst (order-free).
__global__ void k_fill(const int* __restrict__ ew, const int* __restrict__ flag,
                       const float* __restrict__ dis, int* __restrict__ cursor,
                       int2* __restrict__ csr, long e) {
    long i = (long)blockIdx.x * 256 + threadIdx.x;
    if (i >= e) return;
    int shift = *flag;
    int s = ew[i << shift];
    int d = ew[(EE + i) << shift];
    float w = dis[s] * dis[d];
    int pos = atomicAdd(&cursor[d], 1);
    csr[pos] = make_int2(s, __float_as_int(w));
}

// Layer 1 matmul: hw = x @ W1  (x:[N,256], W1:[256,16])
__global__ __launch_bounds__(256) void k_mm1(
    const float* __restrict__ x, const float* __restrict__ W,
    float* __restrict__ hw, int n) {
    __shared__ float Wl[256 * 16];
    int t = threadIdx.x;
#pragma unroll
    for (int i = 0; i < 4; ++i)
        ((float4*)Wl)[t + i * 256] = ((const float4*)W)[t + i * 256];
    __syncthreads();

    int node = blockIdx.x * 256 + t;
    if (node >= n) return;

    const float4* xr = (const float4*)(x + (long)node * 256);
    float acc[16];
#pragma unroll
    for (int o = 0; o < 16; ++o) acc[o] = 0.f;

#pragma unroll 8
    for (int kk = 0; kk < 64; ++kk) {
        float4 xv = xr[kk];
#pragma unroll
        for (int q = 0; q < 4; ++q) {
            float xs = (q == 0) ? xv.x : (q == 1) ? xv.y : (q == 2) ? xv.z : xv.w;
            const float4* wr = (const float4*)&Wl[(kk * 4 + q) * 16];
#pragma unroll
            for (int oo = 0; oo < 4; ++oo) {
                float4 wv = wr[oo];
                acc[oo * 4 + 0] = fmaf(xs, wv.x, acc[oo * 4 + 0]);
                acc[oo * 4 + 1] = fmaf(xs, wv.y, acc[oo * 4 + 1]);
                acc[oo * 4 + 2] = fmaf(xs, wv.z, acc[oo * 4 + 2]);
                acc[oo * 4 + 3] = fmaf(xs, wv.w, acc[oo * 4 + 3]);
            }
        }
    }
    float4* hwo = (float4*)(hw + (long)node * 16);
#pragma unroll
    for (int oo = 0; oo < 4; ++oo)
        hwo[oo] = make_float4(acc[oo * 4], acc[oo * 4 + 1], acc[oo * 4 + 2], acc[oo * 4 + 3]);
}

// 16x16 matmul: hw = h @ W (h already relu'd by the gather epilogue)
__global__ __launch_bounds__(256) void k_mm2(
    const float* __restrict__ h, const float* __restrict__ W,
    float* __restrict__ hw, int n) {
    __shared__ float Wl[256];
    if (threadIdx.x < 64) ((float4*)Wl)[threadIdx.x] = ((const float4*)W)[threadIdx.x];
    __syncthreads();
    int node = blockIdx.x * 256 + threadIdx.x;
    if (node >= n) return;
    float hv[16];
    const float4* hr = (const float4*)(h + (long)node * 16);
#pragma unroll
    for (int i = 0; i < 4; ++i) {
        float4 v = hr[i];
        hv[i * 4 + 0] = v.x; hv[i * 4 + 1] = v.y; hv[i * 4 + 2] = v.z; hv[i * 4 + 3] = v.w;
    }
    float acc[16];
#pragma unroll
    for (int o = 0; o < 16; ++o) acc[o] = 0.f;
#pragma unroll
    for (int k = 0; k < 16; ++k) {
        float xs = hv[k];
#pragma unroll
        for (int o = 0; o < 16; ++o) acc[o] = fmaf(xs, Wl[k * 16 + o], acc[o]);
    }
    float4* hwo = (float4*)(hw + (long)node * 16);
#pragma unroll
    for (int oo = 0; oo < 4; ++oo)
        hwo[oo] = make_float4(acc[oo * 4], acc[oo * 4 + 1], acc[oo * 4 + 2], acc[oo * 4 + 3]);
}

// 16x1 matmul: hw3 = h @ W3 (h already relu'd)
__global__ __launch_bounds__(256) void k_mm3(
    const float* __restrict__ h, const float* __restrict__ W,
    float* __restrict__ hw3, int n) {
    int node = blockIdx.x * 256 + threadIdx.x;
    if (node >= n) return;
    const float4* hr = (const float4*)(h + (long)node * 16);
    float acc = 0.f;
#pragma unroll
    for (int i = 0; i < 4; ++i) {
        float4 v = hr[i];
        acc = fmaf(v.x, W[i * 4 + 0], acc);
        acc = fmaf(v.y, W[i * 4 + 1], acc);
        acc = fmaf(v.z, W[i * 4 + 2], acc);
        acc = fmaf(v.w, W[i * 4 + 3], acc);
    }
    hw3[node] = acc;
}

// Gather-aggregate, 16 channels. Block = 16 nodes x 16 lanes(=channels).
// agg[i,ch] = relu?( b[ch] + dis_i^2*hw[i,ch] + sum_e w_e * hw[src_e,ch] )
template <int RELU>
__global__ __launch_bounds__(256) void k_g16(
    const int* __restrict__ off, const int* __restrict__ deg,
    const int2* __restrict__ csr, const float* __restrict__ dis,
    const float* __restrict__ hw, const float* __restrict__ b,
    float* __restrict__ agg, int n) {
    int t = threadIdx.x;
    int node = blockIdx.x * 16 + (t >> 4);
    int ch = t & 15;
    if (node >= n) return;
    int s0 = off[node];
    int dg = deg[node];
    float acc0 = 0.f, acc1 = 0.f;
    int k = 0;
    for (; k + 1 < dg; k += 2) {
        int2 e0 = csr[s0 + k];
        int2 e1 = csr[s0 + k + 1];
        acc0 = fmaf(__int_as_float(e0.y), hw[(long)e0.x * 16 + ch], acc0);
        acc1 = fmaf(__int_as_float(e1.y), hw[(long)e1.x * 16 + ch], acc1);
    }
    if (k < dg) {
        int2 e0 = csr[s0 + k];
        acc0 = fmaf(__int_as_float(e0.y), hw[(long)e0.x * 16 + ch], acc0);
    }
    float dv = dis[node];
    float r = acc0 + acc1 + dv * dv * hw[(long)node * 16 + ch] + b[ch];
    if (RELU) r = fmaxf(r, 0.f);
    agg[(long)node * 16 + ch] = r;
}

// Gather-aggregate, 1 channel. Block = 16 nodes x 16 lanes; lanes split edges.
__global__ __launch_bounds__(256) void k_g1(
    const int* __restrict__ off, const int* __restrict__ deg,
    const int2* __restrict__ csr, const float* __restrict__ dis,
    const float* __restrict__ hw3, const float* __restrict__ b,
    float* __restrict__ out, int n) {
    int t = threadIdx.x;
    int node = blockIdx.x * 16 + (t >> 4);
    int ln = t & 15;
    if (node >= n) return;
    int s0 = off[node], dg = deg[node];
    float acc = 0.f;
    for (int k = ln; k < dg; k += 16) {
        int2 e = csr[s0 + k];
        acc = fmaf(__int_as_float(e.y), hw3[e.x], acc);
    }
#pragma unroll
    for (int o = 8; o >= 1; o >>= 1) acc += __shfl_down(acc, o, 16);
    if (ln == 0) {
        float dv = dis[node];
        out[node] = fmaf(dv * dv, hw3[node], acc) + b[0];
    }
}

extern "C" void kernel_launch(void* const* d_in, const int* in_sizes, int n_in,
                              void* d_out, int out_size, void* d_ws, size_t ws_size,
                              hipStream_t stream) {
    const float* x  = (const float*)d_in[0];
    const int*   ew = (const int*)d_in[1];
    const float* W1 = (const float*)d_in[2];
    const float* b1 = (const float*)d_in[3];
    const float* W2 = (const float*)d_in[4];
    const float* b2 = (const float*)d_in[5];
    const float* W3 = (const float*)d_in[6];
    const float* b3 = (const float*)d_in[7];
    float* out = (float*)d_out;

    // Workspace layout (4-byte units). csr first for 8B alignment.
    // csr:12.8M | deg:200064 | off:200064 | cursor:200064 | dis:200064 |
    // bsum:1024 | flag:16 | bufA:3.2M | bufB:3.2M   (~81 MB total)
    int2*  csr    = (int2*)d_ws;
    int*   deg    = (int*)(csr + EE);
    int*   off    = deg + 200064;
    int*   cursor = off + 200064;
    float* dis    = (float*)(cursor + 200064);
    int*   bsum   = (int*)(dis + 200064);
    int*   flag   = bsum + 1024;
    float* bufA   = (float*)(flag + 16);          // hw / hw3
    float* bufB   = bufA + 3276800;               // agg / h

    const int n = NN;
    const long e = EE;
    int nb = (n + 255) / 256;              // 782
    int eb = (int)((e + 255) / 256);       // 25000
    int gb = (n + 15) / 16;                // 12500

    k_detect<<<1, 256, 0, stream>>>(ew, flag);
    hipMemsetAsync(deg, 0, 200064 * sizeof(int), stream);
    k_count<<<eb, 256, 0, stream>>>(ew, flag, deg, e);
    k_rsqrt<<<nb, 256, 0, stream>>>(deg, dis, n);

    // CSR build
    k_scan1<<<nb, 256, 0, stream>>>(deg, off, bsum, n);
    k_scan2<<<1, 1024, 0, stream>>>(bsum, nb);
    k_scan3<<<nb, 256, 0, stream>>>(off, bsum, cursor, n);
    k_fill<<<eb, 256, 0, stream>>>(ew, flag, dis, cursor, csr, e);

    // Layer 1
    k_mm1<<<nb, 256, 0, stream>>>(x, W1, bufA, n);
    k_g16<1><<<gb, 256, 0, stream>>>(off, deg, csr, dis, bufA, b1, bufB, n);
    // Layer 2
    k_mm2<<<nb, 256, 0, stream>>>(bufB, W2, bufA, n);
    k_g16<1><<<gb, 256, 0, stream>>>(off, deg, csr, dis, bufA, b2, bufB, n);
    // Layer 3
    k_mm3<<<nb, 256, 0, stream>>>(bufB, W3, bufA, n);
    k_g1<<<gb, 256, 0, stream>>>(off, deg, csr, dis, bufA, b3, out, n);
}